// Round 15
// baseline (272.189 us; speedup 1.0000x reference)
//
#include <hip/hip_runtime.h>
#include <hip/hip_bf16.h>

// BlockAxialDown: pool2x2 -> axial attn (H)+(W) -> relu -> concat -> 1x1 conv
// -> relu -> batch-stat BN -> NCHW.  B=8 C=128 H2=W2=128 E=256, heads=2 dh=64.
//
// attn: quarter ping-pong staging (3 blocks/CU) + (m,c) wave split for the
//   weight GEMMs: each staged B-frag read feeds 2 MFMAs (2 row-bands) ->
//   weight-GEMM LDS reads halved. S^T/softmax/PV per-band (unchanged).
// conv: 64-token blocks (4 blocks/CU). pool: split-channel, high occupancy.

typedef short v8s __attribute__((ext_vector_type(8)));
typedef short v4s __attribute__((ext_vector_type(4)));
typedef float v4f __attribute__((ext_vector_type(4)));
typedef float v4flt __attribute__((ext_vector_type(4)));

#define LSA 136   // attn LDS row stride (bf16)
#define LSC 264   // conv cat row stride
#define LSY 72    // conv y row stride
#define LSQ 66    // pool LDS row stride

static __device__ __forceinline__ short f2bf(float f){
  __hip_bfloat16 h = __float2bfloat16(f);    // RNE -> v_cvt_pk_bf16_f32 pairs
  return __builtin_bit_cast(short, h);
}
static __device__ __forceinline__ float bf2f(short s){
  unsigned u = ((unsigned)(unsigned short)s) << 16;
  return __builtin_bit_cast(float, u);
}

// ---------------- prep: transpose weights to bf16 [out][in]; zero stats ----
__global__ void prep_kernel(const float* __restrict__ Wq_h, const float* __restrict__ Wkv_h,
                            const float* __restrict__ Wout_h, const float* __restrict__ Wq_w,
                            const float* __restrict__ Wkv_w, const float* __restrict__ Wout_w,
                            const float* __restrict__ conv_w, short* __restrict__ wt,
                            float* __restrict__ stats){
  int idx = blockIdx.x * 256 + threadIdx.x;   // 768*256 = 196608 exactly
  if (idx < 8192) stats[idx] = 0.0f;          // 16 copies x 512
  const float* src; int K, O, base;
  if      (idx <  16384){ base = 0;      K=128; O=128; src=Wq_h;  }
  else if (idx <  49152){ base = 16384;  K=128; O=256; src=Wkv_h; }
  else if (idx <  65536){ base = 49152;  K=128; O=128; src=Wout_h;}
  else if (idx <  81920){ base = 65536;  K=128; O=128; src=Wq_w;  }
  else if (idx < 114688){ base = 81920;  K=128; O=256; src=Wkv_w; }
  else if (idx < 131072){ base = 114688; K=128; O=128; src=Wout_w;}
  else                  { base = 131072; K=256; O=256; src=conv_w;}
  int local = idx - base;
  int o = local / K, i = local - o * K;
  wt[idx] = f2bf(src[i * O + o]);   // dst[o][i] = src[i][o]
}

// ---------------- maxpool 2x2 -> bf16 xp[b][h][w][c], split-channel -------
__global__ __launch_bounds__(256, 8)
void pool_kernel(const float* __restrict__ x, short* __restrict__ xp){
  __shared__ short t_[128*LSQ];     // [j][c-half]
  int bx = blockIdx.x;              // (b*128 + i)*2 + chalf
  int chalf = bx & 1;
  int row = bx >> 1;
  int b = row >> 7, i = row & 127;
  int tid = (int)threadIdx.x;
  int j2 = tid & 63;
  int cq = tid >> 6;
  for (int rep = 0; rep < 16; ++rep){
    int cl = cq*16 + rep;
    int c = chalf*64 + cl;
    const float* p0 = x + (((b*128 + c)*256 + 2*i)*256 + 4*j2);
    v4flt a  = *(const v4flt*)p0;
    v4flt bb = *(const v4flt*)(p0 + 256);
    t_[(2*j2)*LSQ + cl]   = f2bf(fmaxf(fmaxf(a[0], a[1]), fmaxf(bb[0], bb[1])));
    t_[(2*j2+1)*LSQ + cl] = f2bf(fmaxf(fmaxf(a[2], a[3]), fmaxf(bb[2], bb[3])));
  }
  __syncthreads();
  int obase = ((b*128 + i)*128)*128 + chalf*64;
  #pragma unroll
  for (int rep = 0; rep < 4; ++rep){
    int idx = rep*256 + tid;
    int r_ = idx >> 3, seg = idx & 7;
    *(v8s*)(xp + obase + r_*128 + seg*8) = *(const v8s*)(&t_[r_*LSQ + seg*8]);
  }
}

// ---------------- fused axial attention ----------------------------------
// 2048 blocks: dir = bx&1. One (b,s) per 512-thr block, 8 waves.
// Weight GEMMs: wave (m = w>>1, c = w&1): rows [32m,32m+32) x staged-quarter
// tile c -> each B-frag feeds 2 MFMAs. S^T/softmax/PV: per band w.
__global__ __launch_bounds__(512, 6)
void attn_kernel(const short* __restrict__ xp, const short* __restrict__ wt,
                 const float* __restrict__ bout_h, const float* __restrict__ bout_w,
                 short* __restrict__ ah, short* __restrict__ aw){
  __shared__ short A[128*LSA];      // 34,816 B
  __shared__ short WB[2][32*LSA];   // 17,408 B

  const int bx = blockIdx.x;
  const int dir = bx & 1;
  const int sb = bx >> 1;
  const int b = sb >> 7, s = sb & 127;
  const int tid = (int)threadIdx.x;
  const int w = tid >> 6;
  const int m = w >> 1;             // row-pair (bands 2m, 2m+1)
  const int c = w & 1;              // tile within staged quarter
  const int lane = tid & 63;
  const int l15 = lane & 15, l4 = lane >> 4;
  const int qrow = tid >> 4;        // 0..31 stage row
  const int qseg = tid & 15;

  const short* Wq   = wt + dir*65536;     // [oc][ic] 128x128 each
  const short* Wk   = Wq + 16384;
  const short* Wv   = Wq + 32768;
  const short* Wout = Wq + 49152;
  const float* bsrc = dir ? bout_w : bout_h;
  short*       ao   = dir ? aw : ah;

  // x A-frags, 2 bands (dir0: 32KB-stride gather; dir1: contiguous)
  const int xb0 = dir ? (((b*128 + s)*128 + (32*m + l15))*128)
                      : (((b*128 + (32*m + l15))*128 + s)*128);
  const int xb1 = dir ? (((b*128 + s)*128 + (32*m + 16 + l15))*128)
                      : (((b*128 + (32*m + 16 + l15))*128 + s)*128);
  v8s av0[4], av1[4];
  #pragma unroll
  for (int kk = 0; kk < 4; ++kk){
    av0[kk] = *(const v8s*)(xp + xb0 + kk*32 + l4*8);
    av1[kk] = *(const v8s*)(xp + xb1 + kk*32 + l4*8);
  }

  v8s rw;                           // one quarter (32x128) in flight
#define LOAD_Q(SRC, QI)  rw = *(const v8s*)((SRC) + (32*(QI) + qrow)*128 + qseg*8);
#define WRITE_Q(SL)      *(v8s*)(&WB[SL][qrow*LSA + qseg*8]) = rw;

  // q/k quarter: tile c x 2 bands -> A [t][oc]
#define QK2(SL, TB)                                                      \
  { int tc = (TB) + c;                                                   \
    v4f d0 = {0.f,0.f,0.f,0.f}, d1 = {0.f,0.f,0.f,0.f};                  \
    _Pragma("unroll")                                                    \
    for (int kk = 0; kk < 4; ++kk){                                      \
      v8s bf = *(const v8s*)(&WB[SL][(c*16 + l15)*LSA + kk*32 + l4*8]);  \
      d0 = __builtin_amdgcn_mfma_f32_16x16x32_bf16(av0[kk], bf, d0, 0, 0, 0); \
      d1 = __builtin_amdgcn_mfma_f32_16x16x32_bf16(av1[kk], bf, d1, 0, 0, 0); \
    }                                                                    \
    _Pragma("unroll")                                                    \
    for (int r = 0; r < 4; ++r){                                         \
      A[(32*m + 4*l4 + r)*LSA + 16*tc + l15]      = f2bf(d0[r]);         \
      A[(32*m + 16 + 4*l4 + r)*LSA + 16*tc + l15] = f2bf(d1[r]);         \
    } }

  // v quarter: tile c x 2 bands -> v^T in A [ch][tok]
#define V2(SL, TB)                                                       \
  { int tc = (TB) + c;                                                   \
    v4f d0 = {0.f,0.f,0.f,0.f}, d1 = {0.f,0.f,0.f,0.f};                  \
    _Pragma("unroll")                                                    \
    for (int kk = 0; kk < 4; ++kk){                                      \
      v8s bf = *(const v8s*)(&WB[SL][(c*16 + l15)*LSA + kk*32 + l4*8]);  \
      d0 = __builtin_amdgcn_mfma_f32_16x16x32_bf16(av0[kk], bf, d0, 0, 0, 0); \
      d1 = __builtin_amdgcn_mfma_f32_16x16x32_bf16(av1[kk], bf, d1, 0, 0, 0); \
    }                                                                    \
    v4s p0, p1;                                                          \
    _Pragma("unroll")                                                    \
    for (int r = 0; r < 4; ++r){ p0[r] = f2bf(d0[r]); p1[r] = f2bf(d1[r]); } \
    *(v4s*)(&A[(16*tc + l15)*LSA + 32*m + 4*l4])      = p0;              \
    *(v4s*)(&A[(16*tc + l15)*LSA + 32*m + 16 + 4*l4]) = p1; }

  // out-proj quarter: tile c x 2 bands; B = ob0/ob1 regs; Z -> A [tok][oc]
#define OP2(SL, TB)                                                      \
  { int tc = (TB) + c;                                                   \
    v4f d0 = {0.f,0.f,0.f,0.f}, d1 = {0.f,0.f,0.f,0.f};                  \
    _Pragma("unroll")                                                    \
    for (int kk = 0; kk < 4; ++kk){                                      \
      v8s awf = *(const v8s*)(&WB[SL][(c*16 + l15)*LSA + kk*32 + l4*8]); \
      d0 = __builtin_amdgcn_mfma_f32_16x16x32_bf16(awf, ob0[kk], d0, 0, 0, 0); \
      d1 = __builtin_amdgcn_mfma_f32_16x16x32_bf16(awf, ob1[kk], d1, 0, 0, 0); \
    }                                                                    \
    v4f bias = *(const v4f*)(bsrc + 16*tc + 4*l4);                       \
    v4s z0, z1;                                                          \
    _Pragma("unroll")                                                    \
    for (int r = 0; r < 4; ++r){                                         \
      z0[r] = f2bf(d0[r] + bias[r]); z1[r] = f2bf(d1[r] + bias[r]); }    \
    *(v4s*)(&A[(32*m + l15)*LSA + 16*tc + 4*l4])      = z0;              \
    *(v4s*)(&A[(32*m + 16 + l15)*LSA + 16*tc + 4*l4]) = z1; }

  // ---- q: quarters 0..3 ----
  LOAD_Q(Wq,0); WRITE_Q(0); LOAD_Q(Wq,1);
  __syncthreads();                  // S1: q-slot0 staged
  QK2(0,0); WRITE_Q(1); LOAD_Q(Wq,2);
  __syncthreads();                  // S2
  QK2(1,2); WRITE_Q(0); LOAD_Q(Wq,3);
  __syncthreads();                  // S3
  QK2(0,4); WRITE_Q(1); LOAD_Q(Wk,0);
  __syncthreads();                  // S4
  QK2(1,6);
  __syncthreads();                  // S5: all q visible (cross-wave)
  v8s bq[2][2];                     // band-w q rows (written by wave pair m=w>>1)
  #pragma unroll
  for (int h = 0; h < 2; ++h)
    #pragma unroll
    for (int kk = 0; kk < 2; ++kk)
      bq[h][kk] = *(const v8s*)(&A[(16*w + l15)*LSA + h*64 + kk*32 + l4*8]);
  WRITE_Q(0); LOAD_Q(Wk,1);
  __syncthreads();                  // S6: k-slot0 staged + bq reads done

  // ---- k: quarters 0..3 (overwrites A) ----
  QK2(0,0); WRITE_Q(1); LOAD_Q(Wk,2);
  __syncthreads();                  // S7
  QK2(1,2); WRITE_Q(0); LOAD_Q(Wk,3);
  __syncthreads();                  // S8
  QK2(0,4); WRITE_Q(1); LOAD_Q(Wv,0);
  __syncthreads();                  // S9
  QK2(1,6); WRITE_Q(0); LOAD_Q(Wv,1);
  __syncthreads();                  // S10: k complete; v-slot0 staged

  // ---- S^T = K.Q^T per head + softmax (band w); stage v1, load v2 under --
  WRITE_Q(1);                       // v1 -> slot1
  v4s pk[2][8];
  #pragma unroll
  for (int h = 0; h < 2; ++h){
    v4f st[8];
    #pragma unroll
    for (int jt = 0; jt < 8; ++jt){
      v4f d = {0.f,0.f,0.f,0.f};
      #pragma unroll
      for (int kk = 0; kk < 2; ++kk){
        v8s ak = *(const v8s*)(&A[(16*jt + l15)*LSA + h*64 + kk*32 + l4*8]);
        d = __builtin_amdgcn_mfma_f32_16x16x32_bf16(ak, bq[h][kk], d, 0, 0, 0);
      }
      st[jt] = d;
    }
    float mx = -1e30f;
    #pragma unroll
    for (int jt = 0; jt < 8; ++jt)
      #pragma unroll
      for (int r = 0; r < 4; ++r) mx = fmaxf(mx, st[jt][r]);
    mx = fmaxf(mx, __shfl_xor(mx, 16));
    mx = fmaxf(mx, __shfl_xor(mx, 32));
    float sm = 0.f;
    #pragma unroll
    for (int jt = 0; jt < 8; ++jt)
      #pragma unroll
      for (int r = 0; r < 4; ++r){
        float e = __expf((st[jt][r] - mx) * 0.125f);   // * dh^-0.5
        st[jt][r] = e; sm += e;
      }
    sm += __shfl_xor(sm, 16);
    sm += __shfl_xor(sm, 32);
    float inv = 1.0f / sm;
    #pragma unroll
    for (int jt = 0; jt < 8; ++jt)
      #pragma unroll
      for (int r = 0; r < 4; ++r) pk[h][jt][r] = f2bf(st[jt][r] * inv);
  }
  LOAD_Q(Wv,2);
  __syncthreads();                  // S11: k reads done (A free); v1 visible

  // ---- P -> own band A; pa readback; reload av for v-phase ----
  v8s pa[2][4];
  #pragma unroll
  for (int h = 0; h < 2; ++h){
    #pragma unroll
    for (int jt = 0; jt < 8; ++jt)
      *(v4s*)(&A[(16*w + l15)*LSA + 16*jt + 4*l4]) = pk[h][jt];
    #pragma unroll
    for (int kk = 0; kk < 4; ++kk)
      pa[h][kk] = *(const v8s*)(&A[(16*w + l15)*LSA + kk*32 + l4*8]);
  }
  #pragma unroll
  for (int kk = 0; kk < 4; ++kk){   // av reload (L2-hit), ready for V2
    av0[kk] = *(const v8s*)(xp + xb0 + kk*32 + l4*8);
    av1[kk] = *(const v8s*)(xp + xb1 + kk*32 + l4*8);
  }
  __syncthreads();                  // S12: pa done (A free for v^T)

  // ---- v: quarters 0..3 -> v^T in A ----
  V2(0,0);
  __syncthreads();                  // S13: slot0 reads done
  V2(1,2); WRITE_Q(0); LOAD_Q(Wv,3);
  __syncthreads();                  // S14
  V2(0,4); WRITE_Q(1);
  __syncthreads();                  // S15
  V2(1,6); LOAD_Q(Wout,0);
  __syncthreads();                  // S16: v^T complete

  // ---- O^T = V^T . P^T (band w); stage wout0, load wout1 under it ----
  WRITE_Q(0);                       // wout0 -> slot0
  v4f ot[2][4];
  #pragma unroll
  for (int h = 0; h < 2; ++h)
    #pragma unroll
    for (int tc = 0; tc < 4; ++tc){
      v4f d = {0.f,0.f,0.f,0.f};
      #pragma unroll
      for (int kk = 0; kk < 4; ++kk){
        v8s vf = *(const v8s*)(&A[(64*h + 16*tc + l15)*LSA + kk*32 + l4*8]);
        d = __builtin_amdgcn_mfma_f32_16x16x32_bf16(vf, pa[h][kk], d, 0, 0, 0);
      }
      ot[h][tc] = d;
    }
  LOAD_Q(Wout,1);
  __syncthreads();                  // S17: v^T reads done; wout0 visible

  // ---- O -> own band A [tok][ch] ----
  #pragma unroll
  for (int h = 0; h < 2; ++h)
    #pragma unroll
    for (int tc = 0; tc < 4; ++tc){
      v4s pko;
      #pragma unroll
      for (int r = 0; r < 4; ++r) pko[r] = f2bf(ot[h][tc][r]);
      *(v4s*)(&A[(16*w + l15)*LSA + 64*h + 16*tc + 4*l4]) = pko;
    }
  __syncthreads();                  // S18: all O visible (cross-wave for ob)

  // ---- ob readback (2 bands); stage wout1; out-proj quarters ----
  v8s ob0[4], ob1[4];
  #pragma unroll
  for (int kk = 0; kk < 4; ++kk){
    ob0[kk] = *(const v8s*)(&A[(32*m + l15)*LSA + kk*32 + l4*8]);
    ob1[kk] = *(const v8s*)(&A[(32*m + 16 + l15)*LSA + kk*32 + l4*8]);
  }
  WRITE_Q(1); LOAD_Q(Wout,2);
  __syncthreads();                  // S19: ob done everywhere; wout1 visible
  OP2(0,0);
  __syncthreads();                  // S20: slot0 reads done
  OP2(1,2); WRITE_Q(0); LOAD_Q(Wout,3);
  __syncthreads();                  // S21: wout2 staged; slot1 reads done
  OP2(0,4); WRITE_Q(1);
  __syncthreads();                  // S22: wout3 staged
  OP2(1,6);
  __syncthreads();                  // S23: Z complete

  int obase = ((b*128 + s)*128)*128;
  #pragma unroll
  for (int r = 0; r < 4; ++r){
    int idx = (r*512 + tid) * 8;
    int t = idx >> 7, cc = idx & 127;
    *(v8s*)(ao + obase + t*128 + cc) = *(const v8s*)(&A[t*LSA + cc]);
  }
#undef LOAD_Q
#undef WRITE_Q
#undef QK2
#undef V2
#undef OP2
}

// ---------------- concat + 1x1 conv + relu + bf16 y + stats ---------------
// 2048 blocks = (b, ii, half): 64 tokens each. 4 blocks/CU.
__global__ __launch_bounds__(512, 4)
void conv_kernel(const short* __restrict__ ah, const short* __restrict__ aw,
                 const short* __restrict__ xp, const short* __restrict__ wt,
                 short* __restrict__ yb, float* __restrict__ stats){
  __shared__ short cats[256*LSY];   // cat [64][LSC] then y [256][LSY]
  __shared__ float lsum[256];
  __shared__ float lsq[256];
  const short* convT = wt + 131072; // [e][f] bf16
  int bx = blockIdx.x;              // (b*128 + ii)*2 + half
  int half = bx & 1;
  int row = bx >> 1;
  int b = row >> 7, ii = row & 127;
  int tid = (int)threadIdx.x;
  int wv = tid >> 6, lane = tid & 63, l15 = lane & 15, l4 = lane >> 4;
  if (tid < 256){ lsum[tid] = 0.f; lsq[tid] = 0.f; }

  v8s wf[2][8];
  #pragma unroll
  for (int x = 0; x < 2; ++x)
    #pragma unroll
    for (int kk = 0; kk < 8; ++kk)
      wf[x][kk] = *(const v8s*)(convT + (((wv + 8*x)*16 + l15)*256) + kk*32 + l4*8);

  #pragma unroll
  for (int r = 0; r < 2; ++r){
    int idx = (r*512 + tid) * 8;
    int t = idx >> 7, c = idx & 127;
    int tg = 64*half + t;
    v8s hv = *(const v8s*)(ah + ((b*128 + tg)*128 + ii)*128 + c);
    v8s wv_ = *(const v8s*)(aw + ((b*128 + ii)*128 + tg)*128 + c);
    v8s o;
    #pragma unroll
    for (int k = 0; k < 8; ++k)
      o[k] = f2bf(fmaxf(bf2f(hv[k]) + bf2f(wv_[k]), 0.f));
    *(v8s*)(&cats[t*LSC + c]) = o;
    *(v8s*)(&cats[t*LSC + 128 + c]) =
        *(const v8s*)(xp + ((b*128 + ii)*128 + tg)*128 + c);
  }
  __syncthreads();

  v4s ypk[2][4];
  float s1[2] = {0.f,0.f}, s2[2] = {0.f,0.f};
  #pragma unroll
  for (int tt = 0; tt < 4; ++tt){
    v4f d0 = {0.f,0.f,0.f,0.f}, d1 = {0.f,0.f,0.f,0.f};
    #pragma unroll
    for (int kk = 0; kk < 8; ++kk){
      v8s af = *(const v8s*)(&cats[(16*tt + l15)*LSC + kk*32 + l4*8]);
      d0 = __builtin_amdgcn_mfma_f32_16x16x32_bf16(af, wf[0][kk], d0, 0, 0, 0);
      d1 = __builtin_amdgcn_mfma_f32_16x16x32_bf16(af, wf[1][kk], d1, 0, 0, 0);
    }
    #pragma unroll
    for (int r = 0; r < 4; ++r){
      float y0 = fmaxf(d0[r], 0.f), y1 = fmaxf(d1[r], 0.f);
      ypk[0][tt][r] = f2bf(y0); ypk[1][tt][r] = f2bf(y1);
      s1[0] += y0; s2[0] += y0*y0;
      s1[1] += y1; s2[1] += y1*y1;
    }
  }
  #pragma unroll
  for (int x = 0; x < 2; ++x){
    s1[x] += __shfl_xor(s1[x], 16); s1[x] += __shfl_xor(s1[x], 32);
    s2[x] += __shfl_xor(s2[x], 16); s2[x] += __shfl_xor(s2[x], 32);
  }
  if (l4 == 0){
    #pragma unroll
    for (int x = 0; x < 2; ++x){
      int e = (wv + 8*x)*16 + l15;
      atomicAdd(&lsum[e], s1[x]);
      atomicAdd(&lsq[e],  s2[x]);
    }
  }
  __syncthreads();                  // reuse cats as y [256][LSY]
  #pragma unroll
  for (int x = 0; x < 2; ++x)
    #pragma unroll
    for (int tt = 0; tt < 4; ++tt)
      *(v4s*)(&cats[((wv + 8*x)*16 + l15)*LSY + 16*tt + 4*l4]) = ypk[x][tt];
  __syncthreads();
  #pragma unroll
  for (int r = 0; r < 4; ++r){
    int idxv = r*512 + tid;
    int e = idxv >> 3, jseg = idxv & 7;
    *(v8s*)(yb + ((b*256 + e)*128 + ii)*128 + 64*half + jseg*8) =
        *(const v8s*)(&cats[e*LSY + jseg*8]);
  }
  if (tid < 256){
    int c = bx & 15;
    atomicAdd(&stats[c*512 + tid],       lsum[tid]);
    atomicAdd(&stats[c*512 + 256 + tid], lsq[tid]);
  }
}

// ---------------- BN: bf16 y -> fp32 out, block = one (b,e) plane ---------
__global__ void bn_kernel(const short* __restrict__ yb, float* __restrict__ out,
                          const float* __restrict__ stats,
                          const float* __restrict__ gamma, const float* __restrict__ beta){
  const float invn = 1.0f / 131072.0f;
  int bx = blockIdx.x;              // b*256 + e
  int e = bx & 255;
  float s1 = 0.f, s2 = 0.f;
  #pragma unroll
  for (int c = 0; c < 16; ++c){
    s1 += stats[c*512 + e];
    s2 += stats[c*512 + 256 + e];
  }
  float m   = s1 * invn;
  float var = s2 * invn - m * m;
  float sc  = gamma[e] * rsqrtf(var + 1e-5f);
  float sh  = beta[e] - m * sc;
  int base = bx * 16384;
  int tid = (int)threadIdx.x;       // 256
  for (int rep = 0; rep < 8; ++rep){
    int idx = base + (rep*256 + tid)*8;
    v8s yv = *(const v8s*)(yb + idx);
    v4f o1, o2;
    #pragma unroll
    for (int r = 0; r < 4; ++r){
      o1[r] = bf2f(yv[r])   * sc + sh;
      o2[r] = bf2f(yv[4+r]) * sc + sh;
    }
    *(v4f*)(out + idx)     = o1;
    *(v4f*)(out + idx + 4) = o2;
  }
}

extern "C" void kernel_launch(void* const* d_in, const int* in_sizes, int n_in,
                              void* d_out, int out_size, void* d_ws, size_t ws_size,
                              hipStream_t stream){
  const float* x      = (const float*)d_in[0];
  const float* Wq_h   = (const float*)d_in[1];
  const float* Wkv_h  = (const float*)d_in[2];
  const float* Wout_h = (const float*)d_in[3];
  const float* bout_h = (const float*)d_in[4];
  const float* Wq_w   = (const float*)d_in[5];
  const float* Wkv_w  = (const float*)d_in[6];
  const float* Wout_w = (const float*)d_in[7];
  const float* bout_w = (const float*)d_in[8];
  const float* conv_w = (const float*)d_in[9];
  const float* gamma  = (const float*)d_in[10];
  const float* beta   = (const float*)d_in[11];
  float* out = (float*)d_out;

  char* ws = (char*)d_ws;
  short* xp    = (short*)(ws);               // [0, 33554432)
  short* ah    = (short*)(ws +  33554432);   // [33554432, 67108864)
  short* aw    = (short*)(ws +  67108864);   // [67108864, 100663296)
  short* yb    = (short*)(ws + 100663296);   // [100663296, 167772160)
  short* wt    = (short*)(ws + 167772160);   // [167772160, 168165376)
  float* stats = (float*)(ws + 168165376);   // [168165376, 168198144)

  prep_kernel<<<768, 256, 0, stream>>>(Wq_h, Wkv_h, Wout_h, Wq_w, Wkv_w, Wout_w,
                                       conv_w, wt, stats);
  pool_kernel<<<2048, 256, 0, stream>>>(x, xp);
  attn_kernel<<<2048, 512, 0, stream>>>(xp, wt, bout_h, bout_w, ah, aw);
  conv_kernel<<<2048, 512, 0, stream>>>(ah, aw, xp, wt, yb, stats);
  bn_kernel<<<2048, 256, 0, stream>>>(yb, out, stats, gamma, beta);
}

// Round 16
// 252.964 us; speedup vs baseline: 1.0760x; 1.0760x over previous
//
#include <hip/hip_runtime.h>
#include <hip/hip_bf16.h>

// BlockAxialDown: pool2x2 -> axial attn (H)+(W) -> relu -> concat -> 1x1 conv
// -> relu -> batch-stat BN -> NCHW.  B=8 C=128 H2=W2=128 E=256, heads=2 dh=64.
//
// attn: quarter ping-pong weight staging (2x32-row slots, 17.4KB; LDS 52.2KB,
//   3 blocks/CU). Every barrier segment: compute(slot a) || ds-write(slot b)
//   || global-load(next quarter). Zero write-only stall segments.
// conv: 64-token blocks (4 blocks/CU), weight frags in regs.
// pool: split-channel blocks (2048), 16.9KB LDS -> high occupancy.
// (R16 = revert to measured-best R14; R15's B-frag-reuse split regressed.)

typedef short v8s __attribute__((ext_vector_type(8)));
typedef short v4s __attribute__((ext_vector_type(4)));
typedef float v4f __attribute__((ext_vector_type(4)));
typedef float v4flt __attribute__((ext_vector_type(4)));

#define LSA 136   // attn LDS row stride (bf16)
#define LSC 264   // conv cat row stride
#define LSY 72    // conv y row stride (144B, 16B-aligned v8s)
#define LSQ 66    // pool LDS row stride (c-half 64 + 2)

static __device__ __forceinline__ short f2bf(float f){
  __hip_bfloat16 h = __float2bfloat16(f);    // RNE -> v_cvt_pk_bf16_f32 pairs
  return __builtin_bit_cast(short, h);
}
static __device__ __forceinline__ float bf2f(short s){
  unsigned u = ((unsigned)(unsigned short)s) << 16;
  return __builtin_bit_cast(float, u);
}

// ---------------- prep: transpose weights to bf16 [out][in]; zero stats ----
__global__ void prep_kernel(const float* __restrict__ Wq_h, const float* __restrict__ Wkv_h,
                            const float* __restrict__ Wout_h, const float* __restrict__ Wq_w,
                            const float* __restrict__ Wkv_w, const float* __restrict__ Wout_w,
                            const float* __restrict__ conv_w, short* __restrict__ wt,
                            float* __restrict__ stats){
  int idx = blockIdx.x * 256 + threadIdx.x;   // 768*256 = 196608 exactly
  if (idx < 8192) stats[idx] = 0.0f;          // 16 copies x 512
  const float* src; int K, O, base;
  if      (idx <  16384){ base = 0;      K=128; O=128; src=Wq_h;  }
  else if (idx <  49152){ base = 16384;  K=128; O=256; src=Wkv_h; }
  else if (idx <  65536){ base = 49152;  K=128; O=128; src=Wout_h;}
  else if (idx <  81920){ base = 65536;  K=128; O=128; src=Wq_w;  }
  else if (idx < 114688){ base = 81920;  K=128; O=256; src=Wkv_w; }
  else if (idx < 131072){ base = 114688; K=128; O=128; src=Wout_w;}
  else                  { base = 131072; K=256; O=256; src=conv_w;}
  int local = idx - base;
  int o = local / K, i = local - o * K;
  wt[idx] = f2bf(src[i * O + o]);   // dst[o][i] = src[i][o]
}

// ---------------- maxpool 2x2 -> bf16 xp[b][h][w][c], split-channel -------
__global__ __launch_bounds__(256, 8)
void pool_kernel(const float* __restrict__ x, short* __restrict__ xp){
  __shared__ short t_[128*LSQ];     // [j][c-half]
  int bx = blockIdx.x;              // (b*128 + i)*2 + chalf
  int chalf = bx & 1;
  int row = bx >> 1;
  int b = row >> 7, i = row & 127;
  int tid = (int)threadIdx.x;
  int j2 = tid & 63;                // lane handles output cols 2*j2, 2*j2+1
  int cq = tid >> 6;                // 4 channel groups
  for (int rep = 0; rep < 16; ++rep){
    int cl = cq*16 + rep;           // 0..63 within half
    int c = chalf*64 + cl;
    const float* p0 = x + (((b*128 + c)*256 + 2*i)*256 + 4*j2);
    v4flt a  = *(const v4flt*)p0;          // 16B coalesced
    v4flt bb = *(const v4flt*)(p0 + 256);
    t_[(2*j2)*LSQ + cl]   = f2bf(fmaxf(fmaxf(a[0], a[1]), fmaxf(bb[0], bb[1])));
    t_[(2*j2+1)*LSQ + cl] = f2bf(fmaxf(fmaxf(a[2], a[3]), fmaxf(bb[2], bb[3])));
  }
  __syncthreads();
  int obase = ((b*128 + i)*128)*128 + chalf*64;  // xp[b][i][j][c-half base]
  #pragma unroll
  for (int rep = 0; rep < 4; ++rep){
    int idx = rep*256 + tid;                   // 1024 v8s total
    int r_ = idx >> 3, seg = idx & 7;          // r_=j, seg*8=c offset
    *(v8s*)(xp + obase + r_*128 + seg*8) = *(const v8s*)(&t_[r_*LSQ + seg*8]);
  }
}

// ---------------- fused axial attention, quarter ping-pong ----------------
// 2048 blocks: dir = bx&1. One (b,s) per 512-thr block, 8 waves = 16-token
// bands. WB = 2 slots x 32 oc rows. Each segment: compute || write || load.
__global__ __launch_bounds__(512, 6)
void attn_kernel(const short* __restrict__ xp, const short* __restrict__ wt,
                 const float* __restrict__ bout_h, const float* __restrict__ bout_w,
                 short* __restrict__ ah, short* __restrict__ aw){
  __shared__ short A[128*LSA];      // 34,816 B
  __shared__ short WB[2][32*LSA];   // 17,408 B

  const int bx = blockIdx.x;
  const int dir = bx & 1;
  const int sb = bx >> 1;
  const int b = sb >> 7, s = sb & 127;
  const int tid = (int)threadIdx.x;
  const int w = tid >> 6;
  const int lane = tid & 63;
  const int l15 = lane & 15, l4 = lane >> 4;
  const int qrow = tid >> 4;        // 0..31 (stage row)
  const int qseg = tid & 15;        // 16B segment

  const short* Wq   = wt + dir*65536;     // [oc][ic] 128x128 each
  const short* Wk   = Wq + 16384;
  const short* Wv   = Wq + 32768;
  const short* Wout = Wq + 49152;
  const float* bsrc = dir ? bout_w : bout_h;
  short*       ao   = dir ? aw : ah;

  // x A-frags (dir0: 32KB-stride gather; dir1: contiguous)
  const int trow = 16*w + l15;
  const int xbase = dir ? (((b*128 + s)*128 + trow)*128)
                        : (((b*128 + trow)*128 + s)*128);
  v8s av[4];
  #pragma unroll
  for (int kk = 0; kk < 4; ++kk)
    av[kk] = *(const v8s*)(xp + xbase + kk*32 + l4*8);

  v8s rw;                           // one quarter (32x128) in flight
#define LOAD_Q(SRC, QI)  rw = *(const v8s*)((SRC) + (32*(QI) + qrow)*128 + qseg*8);
#define WRITE_Q(SL)      *(v8s*)(&WB[SL][qrow*LSA + qseg*8]) = rw;

  // q/k quarter: 2 col-tiles -> A [t][c] own band
#define QK_Q(SL, TB)                                                     \
  { _Pragma("unroll")                                                    \
    for (int tcl = 0; tcl < 2; ++tcl){                                   \
      int tc = (TB) + tcl;                                               \
      v4f d = {0.f,0.f,0.f,0.f};                                         \
      _Pragma("unroll")                                                  \
      for (int kk = 0; kk < 4; ++kk){                                    \
        v8s bf = *(const v8s*)(&WB[SL][(tcl*16 + l15)*LSA + kk*32 + l4*8]); \
        d = __builtin_amdgcn_mfma_f32_16x16x32_bf16(av[kk], bf, d, 0, 0, 0); \
      }                                                                  \
      _Pragma("unroll")                                                  \
      for (int r = 0; r < 4; ++r)                                        \
        A[(16*w + 4*l4 + r)*LSA + 16*tc + l15] = f2bf(d[r]);             \
    } }

  // v quarter: 2 col-tiles -> v^T in A [ch][tok]
#define V_Q(SL, TB)                                                      \
  { _Pragma("unroll")                                                    \
    for (int tcl = 0; tcl < 2; ++tcl){                                   \
      int tc = (TB) + tcl;                                               \
      v4f d = {0.f,0.f,0.f,0.f};                                         \
      _Pragma("unroll")                                                  \
      for (int kk = 0; kk < 4; ++kk){                                    \
        v8s bf = *(const v8s*)(&WB[SL][(tcl*16 + l15)*LSA + kk*32 + l4*8]); \
        d = __builtin_amdgcn_mfma_f32_16x16x32_bf16(av[kk], bf, d, 0, 0, 0); \
      }                                                                  \
      v4s pkv;                                                           \
      _Pragma("unroll")                                                  \
      for (int r = 0; r < 4; ++r) pkv[r] = f2bf(d[r]);                   \
      *(v4s*)(&A[(16*tc + l15)*LSA + 16*w + 4*l4]) = pkv;                \
    } }

  // out-proj quarter: 2 col-tiles, B = ob regs; Z -> A own band
#define OP_Q(SL, TB)                                                     \
  { _Pragma("unroll")                                                    \
    for (int tcl = 0; tcl < 2; ++tcl){                                   \
      int tc = (TB) + tcl;                                               \
      v4f d = {0.f,0.f,0.f,0.f};                                         \
      _Pragma("unroll")                                                  \
      for (int kk = 0; kk < 4; ++kk){                                    \
        v8s awf = *(const v8s*)(&WB[SL][(tcl*16 + l15)*LSA + kk*32 + l4*8]); \
        d = __builtin_amdgcn_mfma_f32_16x16x32_bf16(awf, ob[kk], d, 0, 0, 0); \
      }                                                                  \
      v4f bias = *(const v4f*)(bsrc + 16*tc + 4*l4);                     \
      v4s z;                                                             \
      _Pragma("unroll")                                                  \
      for (int r = 0; r < 4; ++r) z[r] = f2bf(d[r] + bias[r]);           \
      *(v4s*)(&A[(16*w + l15)*LSA + 16*tc + 4*l4]) = z;                  \
    } }

  // ---- q: quarters 0..3 ----
  LOAD_Q(Wq,0); WRITE_Q(0);
  LOAD_Q(Wq,1);
  __syncthreads();                  // S1: q0 staged
  QK_Q(0,0); WRITE_Q(1); LOAD_Q(Wq,2);
  __syncthreads();                  // S2
  QK_Q(1,2); WRITE_Q(0); LOAD_Q(Wq,3);
  __syncthreads();                  // S3
  QK_Q(0,4); WRITE_Q(1); LOAD_Q(Wk,0);
  __syncthreads();                  // S4
  QK_Q(1,6); WRITE_Q(0); LOAD_Q(Wk,1);
  v8s bq[2][2];                     // q complete in own band (wave-local)
  #pragma unroll
  for (int h = 0; h < 2; ++h)
    #pragma unroll
    for (int kk = 0; kk < 2; ++kk)
      bq[h][kk] = *(const v8s*)(&A[(16*w + l15)*LSA + h*64 + kk*32 + l4*8]);
  __syncthreads();                  // S5: k0 staged (q in A now dead)

  // ---- k: quarters 0..3 (overwrites A) ----
  QK_Q(0,0); WRITE_Q(1); LOAD_Q(Wk,2);
  __syncthreads();                  // S6
  QK_Q(1,2); WRITE_Q(0); LOAD_Q(Wk,3);
  __syncthreads();                  // S7
  QK_Q(0,4); WRITE_Q(1); LOAD_Q(Wv,0);
  __syncthreads();                  // S8
  QK_Q(1,6); WRITE_Q(0); LOAD_Q(Wv,1);
  __syncthreads();                  // S9: k complete; v0 in slot0

  // ---- S^T = K.Q^T per head + softmax; stage v1 + load v2 under it ----
  WRITE_Q(1);                       // v1 -> slot1
  v4s pk[2][8];
  #pragma unroll
  for (int h = 0; h < 2; ++h){
    v4f st[8];
    #pragma unroll
    for (int jt = 0; jt < 8; ++jt){
      v4f d = {0.f,0.f,0.f,0.f};
      #pragma unroll
      for (int kk = 0; kk < 2; ++kk){
        v8s ak = *(const v8s*)(&A[(16*jt + l15)*LSA + h*64 + kk*32 + l4*8]);
        d = __builtin_amdgcn_mfma_f32_16x16x32_bf16(ak, bq[h][kk], d, 0, 0, 0);
      }
      st[jt] = d;
    }
    float mx = -1e30f;
    #pragma unroll
    for (int jt = 0; jt < 8; ++jt)
      #pragma unroll
      for (int r = 0; r < 4; ++r) mx = fmaxf(mx, st[jt][r]);
    mx = fmaxf(mx, __shfl_xor(mx, 16));
    mx = fmaxf(mx, __shfl_xor(mx, 32));
    float sm = 0.f;
    #pragma unroll
    for (int jt = 0; jt < 8; ++jt)
      #pragma unroll
      for (int r = 0; r < 4; ++r){
        float e = __expf((st[jt][r] - mx) * 0.125f);   // * dh^-0.5
        st[jt][r] = e; sm += e;
      }
    sm += __shfl_xor(sm, 16);
    sm += __shfl_xor(sm, 32);
    float inv = 1.0f / sm;
    #pragma unroll
    for (int jt = 0; jt < 8; ++jt)
      #pragma unroll
      for (int r = 0; r < 4; ++r) pk[h][jt][r] = f2bf(st[jt][r] * inv);
  }
  LOAD_Q(Wv,2);
  __syncthreads();                  // S10: k reads done (A free); v1 visible

  // ---- P -> own band A; readback pa ----
  v8s pa[2][4];
  #pragma unroll
  for (int h = 0; h < 2; ++h){
    #pragma unroll
    for (int jt = 0; jt < 8; ++jt)
      *(v4s*)(&A[(16*w + l15)*LSA + 16*jt + 4*l4]) = pk[h][jt];
    #pragma unroll
    for (int kk = 0; kk < 4; ++kk)
      pa[h][kk] = *(const v8s*)(&A[(16*w + l15)*LSA + kk*32 + l4*8]);
  }
  __syncthreads();                  // S11: pa done (A free for v^T)

  // ---- v: quarters 0..3 -> v^T in A ----
  V_Q(0,0);
  __syncthreads();                  // S12: slot0 reads done
  V_Q(1,2); WRITE_Q(0); LOAD_Q(Wv,3);
  __syncthreads();                  // S13
  V_Q(0,4); WRITE_Q(1);             // v3 -> slot1
  __syncthreads();                  // S14
  V_Q(1,6); LOAD_Q(Wout,0);
  __syncthreads();                  // S15: v^T complete

  // ---- O^T = V^T . P^T; stage wout0 + load wout1 under it ----
  WRITE_Q(0);                       // wout0 -> slot0
  v4f ot[2][4];
  #pragma unroll
  for (int h = 0; h < 2; ++h)
    #pragma unroll
    for (int tc = 0; tc < 4; ++tc){
      v4f d = {0.f,0.f,0.f,0.f};
      #pragma unroll
      for (int kk = 0; kk < 4; ++kk){
        v8s vf = *(const v8s*)(&A[(64*h + 16*tc + l15)*LSA + kk*32 + l4*8]);
        d = __builtin_amdgcn_mfma_f32_16x16x32_bf16(vf, pa[h][kk], d, 0, 0, 0);
      }
      ot[h][tc] = d;
    }
  LOAD_Q(Wout,1);
  __syncthreads();                  // S16: v^T reads done; wout0 visible

  // ---- O -> own band A; ob; out-proj quarters 0..3 ----
  #pragma unroll
  for (int h = 0; h < 2; ++h)
    #pragma unroll
    for (int tc = 0; tc < 4; ++tc){
      v4s pko;
      #pragma unroll
      for (int r = 0; r < 4; ++r) pko[r] = f2bf(ot[h][tc][r]);
      *(v4s*)(&A[(16*w + l15)*LSA + 64*h + 16*tc + 4*l4]) = pko;
    }
  v8s ob[4];
  #pragma unroll
  for (int kk = 0; kk < 4; ++kk)
    ob[kk] = *(const v8s*)(&A[(16*w + l15)*LSA + kk*32 + l4*8]);
  OP_Q(0,0); WRITE_Q(1); LOAD_Q(Wout,2);
  __syncthreads();                  // S17: slot0 reads done; wout1 visible
  OP_Q(1,2); WRITE_Q(0); LOAD_Q(Wout,3);
  __syncthreads();                  // S18
  OP_Q(0,4); WRITE_Q(1);
  __syncthreads();                  // S19
  OP_Q(1,6);
  __syncthreads();                  // S20: Z complete

  int obase = ((b*128 + s)*128)*128;
  #pragma unroll
  for (int r = 0; r < 4; ++r){
    int idx = (r*512 + tid) * 8;
    int t = idx >> 7, c = idx & 127;
    *(v8s*)(ao + obase + t*128 + c) = *(const v8s*)(&A[t*LSA + c]);
  }
#undef LOAD_Q
#undef WRITE_Q
#undef QK_Q
#undef V_Q
#undef OP_Q
}

// ---------------- concat + 1x1 conv + relu + bf16 y + stats ---------------
// 2048 blocks = (b, ii, half): 64 tokens each. LDS 38.9KB -> 4 blocks/CU.
__global__ __launch_bounds__(512, 4)
void conv_kernel(const short* __restrict__ ah, const short* __restrict__ aw,
                 const short* __restrict__ xp, const short* __restrict__ wt,
                 short* __restrict__ yb, float* __restrict__ stats){
  __shared__ short cats[256*LSY];   // cat [64][LSC] then y [256][LSY]
  __shared__ float lsum[256];
  __shared__ float lsq[256];
  const short* convT = wt + 131072; // [e][f] bf16
  int bx = blockIdx.x;              // (b*128 + ii)*2 + half
  int half = bx & 1;
  int row = bx >> 1;
  int b = row >> 7, ii = row & 127;
  int tid = (int)threadIdx.x;
  int wv = tid >> 6, lane = tid & 63, l15 = lane & 15, l4 = lane >> 4;
  if (tid < 256){ lsum[tid] = 0.f; lsq[tid] = 0.f; }

  v8s wf[2][8];
  #pragma unroll
  for (int x = 0; x < 2; ++x)
    #pragma unroll
    for (int kk = 0; kk < 8; ++kk)
      wf[x][kk] = *(const v8s*)(convT + (((wv + 8*x)*16 + l15)*256) + kk*32 + l4*8);

  #pragma unroll
  for (int r = 0; r < 2; ++r){
    int idx = (r*512 + tid) * 8;
    int t = idx >> 7, c = idx & 127;
    int tg = 64*half + t;
    v8s hv = *(const v8s*)(ah + ((b*128 + tg)*128 + ii)*128 + c);
    v8s wv_ = *(const v8s*)(aw + ((b*128 + ii)*128 + tg)*128 + c);
    v8s o;
    #pragma unroll
    for (int k = 0; k < 8; ++k)
      o[k] = f2bf(fmaxf(bf2f(hv[k]) + bf2f(wv_[k]), 0.f));
    *(v8s*)(&cats[t*LSC + c]) = o;
    *(v8s*)(&cats[t*LSC + 128 + c]) =
        *(const v8s*)(xp + ((b*128 + ii)*128 + tg)*128 + c);
  }
  __syncthreads();

  v4s ypk[2][4];
  float s1[2] = {0.f,0.f}, s2[2] = {0.f,0.f};
  #pragma unroll
  for (int tt = 0; tt < 4; ++tt){
    v4f d0 = {0.f,0.f,0.f,0.f}, d1 = {0.f,0.f,0.f,0.f};
    #pragma unroll
    for (int kk = 0; kk < 8; ++kk){
      v8s af = *(const v8s*)(&cats[(16*tt + l15)*LSC + kk*32 + l4*8]);
      d0 = __builtin_amdgcn_mfma_f32_16x16x32_bf16(af, wf[0][kk], d0, 0, 0, 0);
      d1 = __builtin_amdgcn_mfma_f32_16x16x32_bf16(af, wf[1][kk], d1, 0, 0, 0);
    }
    #pragma unroll
    for (int r = 0; r < 4; ++r){
      float y0 = fmaxf(d0[r], 0.f), y1 = fmaxf(d1[r], 0.f);
      ypk[0][tt][r] = f2bf(y0); ypk[1][tt][r] = f2bf(y1);
      s1[0] += y0; s2[0] += y0*y0;
      s1[1] += y1; s2[1] += y1*y1;
    }
  }
  #pragma unroll
  for (int x = 0; x < 2; ++x){
    s1[x] += __shfl_xor(s1[x], 16); s1[x] += __shfl_xor(s1[x], 32);
    s2[x] += __shfl_xor(s2[x], 16); s2[x] += __shfl_xor(s2[x], 32);
  }
  if (l4 == 0){
    #pragma unroll
    for (int x = 0; x < 2; ++x){
      int e = (wv + 8*x)*16 + l15;
      atomicAdd(&lsum[e], s1[x]);
      atomicAdd(&lsq[e],  s2[x]);
    }
  }
  __syncthreads();                  // reuse cats as y [256][LSY]
  #pragma unroll
  for (int x = 0; x < 2; ++x)
    #pragma unroll
    for (int tt = 0; tt < 4; ++tt)
      *(v4s*)(&cats[((wv + 8*x)*16 + l15)*LSY + 16*tt + 4*l4]) = ypk[x][tt];
  __syncthreads();
  #pragma unroll
  for (int r = 0; r < 4; ++r){      // coalesced bf16 y store (64 j per e)
    int idxv = r*512 + tid;         // 2048 v8s
    int e = idxv >> 3, jseg = idxv & 7;
    *(v8s*)(yb + ((b*256 + e)*128 + ii)*128 + 64*half + jseg*8) =
        *(const v8s*)(&cats[e*LSY + jseg*8]);
  }
  if (tid < 256){
    int c = bx & 15;                // 16-way spread
    atomicAdd(&stats[c*512 + tid],       lsum[tid]);
    atomicAdd(&stats[c*512 + 256 + tid], lsq[tid]);
  }
}

// ---------------- BN: bf16 y -> fp32 out, block = one (b,e) plane ---------
__global__ void bn_kernel(const short* __restrict__ yb, float* __restrict__ out,
                          const float* __restrict__ stats,
                          const float* __restrict__ gamma, const float* __restrict__ beta){
  const float invn = 1.0f / 131072.0f;
  int bx = blockIdx.x;              // b*256 + e
  int e = bx & 255;
  float s1 = 0.f, s2 = 0.f;
  #pragma unroll
  for (int c = 0; c < 16; ++c){
    s1 += stats[c*512 + e];
    s2 += stats[c*512 + 256 + e];
  }
  float m   = s1 * invn;
  float var = s2 * invn - m * m;
  float sc  = gamma[e] * rsqrtf(var + 1e-5f);
  float sh  = beta[e] - m * sc;
  int base = bx * 16384;
  int tid = (int)threadIdx.x;       // 256
  for (int rep = 0; rep < 8; ++rep){
    int idx = base + (rep*256 + tid)*8;
    v8s yv = *(const v8s*)(yb + idx);
    v4f o1, o2;
    #pragma unroll
    for (int r = 0; r < 4; ++r){
      o1[r] = bf2f(yv[r])   * sc + sh;
      o2[r] = bf2f(yv[4+r]) * sc + sh;
    }
    *(v4f*)(out + idx)     = o1;
    *(v4f*)(out + idx + 4) = o2;
  }
}

extern "C" void kernel_launch(void* const* d_in, const int* in_sizes, int n_in,
                              void* d_out, int out_size, void* d_ws, size_t ws_size,
                              hipStream_t stream){
  const float* x      = (const float*)d_in[0];
  const float* Wq_h   = (const float*)d_in[1];
  const float* Wkv_h  = (const float*)d_in[2];
  const float* Wout_h = (const float*)d_in[3];
  const float* bout_h = (const float*)d_in[4];
  const float* Wq_w   = (const float*)d_in[5];
  const float* Wkv_w  = (const float*)d_in[6];
  const float* Wout_w = (const float*)d_in[7];
  const float* bout_w = (const float*)d_in[8];
  const float* conv_w = (const float*)d_in[9];
  const float* gamma  = (const float*)d_in[10];
  const float* beta   = (const float*)d_in[11];
  float* out = (float*)d_out;

  char* ws = (char*)d_ws;
  short* xp    = (short*)(ws);               // [0, 33554432)            bf16 [b][h][w][c]
  short* ah    = (short*)(ws +  33554432);   // [33554432, 67108864)     bf16 [b][w][h][c]
  short* aw    = (short*)(ws +  67108864);   // [67108864, 100663296)    bf16 [b][h][w][c]
  short* yb    = (short*)(ws + 100663296);   // [100663296, 167772160)   bf16 [b][e][h][w]
  short* wt    = (short*)(ws + 167772160);   // [167772160, 168165376)   bf16 W^T pack
  float* stats = (float*)(ws + 168165376);   // [168165376, 168198144)   BN sums x16

  prep_kernel<<<768, 256, 0, stream>>>(Wq_h, Wkv_h, Wout_h, Wq_w, Wkv_w, Wout_w,
                                       conv_w, wt, stats);
  pool_kernel<<<2048, 256, 0, stream>>>(x, xp);
  attn_kernel<<<2048, 512, 0, stream>>>(xp, wt, bout_h, bout_w, ah, aw);
  conv_kernel<<<2048, 512, 0, stream>>>(ah, aw, xp, wt, yb, stats);
  bn_kernel<<<2048, 256, 0, stream>>>(yb, out, stats, gamma, beta);
}